// Round 1
// baseline (133.715 us; speedup 1.0000x reference)
//
#include <hip/hip_runtime.h>

#define N_NODES 50000
#define E_EDGES 800000
#define NTILES  (E_EDGES / 16)   // 50000 exact

typedef __attribute__((ext_vector_type(8))) short short8;
typedef __attribute__((ext_vector_type(4))) float floatx4;

// float -> bf16 bits, round-to-nearest-even
__device__ __forceinline__ short f2bf(float x) {
    union { float f; unsigned u; } v; v.f = x;
    unsigned r = v.u + 0x7FFFu + ((v.u >> 16) & 1u);
    return (short)(r >> 16);
}

// Kernel A: per-node LayerNorm+ReLU -> h; out = bias + h @ root
__global__ __launch_bounds__(256) void node_kernel(
    const float* __restrict__ x, const float* __restrict__ gamma,
    const float* __restrict__ beta, const float* __restrict__ root,
    const float* __restrict__ bias, float* __restrict__ h,
    float* __restrict__ out)
{
    int n = blockIdx.x * blockDim.x + threadIdx.x;
    if (n >= N_NODES) return;
    const float* xr = x + n * 16;
    float xv[16];
    #pragma unroll
    for (int i = 0; i < 4; ++i) ((floatx4*)xv)[i] = ((const floatx4*)xr)[i];
    float mu = 0.f;
    #pragma unroll
    for (int i = 0; i < 16; ++i) mu += xv[i];
    mu *= (1.f / 16.f);
    float var = 0.f;
    #pragma unroll
    for (int i = 0; i < 16; ++i) { float d = xv[i] - mu; var += d * d; }
    var *= (1.f / 16.f);
    float rs = rsqrtf(var + 1e-5f);
    float hv[16];
    #pragma unroll
    for (int i = 0; i < 16; ++i) {
        float t = (xv[i] - mu) * rs * gamma[i] + beta[i];
        hv[i] = t > 0.f ? t : 0.f;
    }
    float* hr = h + n * 16;
    #pragma unroll
    for (int i = 0; i < 4; ++i) ((floatx4*)hr)[i] = ((floatx4*)hv)[i];
    // out init = bias + h @ root   (root is [16,16] row-major: root[i*16+o])
    float ov[16];
    #pragma unroll
    for (int o = 0; o < 16; ++o) ov[o] = bias[o];
    #pragma unroll
    for (int i = 0; i < 16; ++i) {
        float hi = hv[i];
        #pragma unroll
        for (int o = 0; o < 16; ++o) ov[o] += hi * root[i * 16 + o];
    }
    float* orow = out + n * 16;
    #pragma unroll
    for (int i = 0; i < 4; ++i) ((floatx4*)orow)[i] = ((floatx4*)ov)[i];
}

// Kernel B: per-wave tile of 16 edges.
// msg[e,o] = sum_k z[e,k] * W2[k,o],  z[e,t*16+i] = ea[e,t]*h[src,i]  (k<128)
//            plus K rows 128..143: z = h[src,i], W2 = b_edge[i*16+o]; 144..159 zero.
// D via mfma_f32_16x16x32_bf16, 5 K-chunks. Then atomic scatter into out[dst].
__global__ __launch_bounds__(256) void edge_kernel(
    const int* __restrict__ eidx, const float* __restrict__ ea,
    const float* __restrict__ w_edge, const float* __restrict__ b_edge,
    const float* __restrict__ h, float* __restrict__ out)
{
    const int lane = threadIdx.x & 63;
    const int wid  = threadIdx.x >> 6;
    const int m = lane & 15;   // edge-in-tile for A; output col for C/D and B
    const int q = lane >> 4;   // quad

    // B fragments: lane holds B[k0+j][m], k0 = 32c + 8q
    short8 bfrag[5];
    #pragma unroll
    for (int c = 0; c < 5; ++c) {
        short8 f;
        #pragma unroll
        for (int j = 0; j < 8; ++j) {
            int k = 32 * c + 8 * q + j;
            float v = 0.f;
            if (k < 128)      v = w_edge[(k >> 4) * 256 + (k & 15) * 16 + m];
            else if (k < 144) v = b_edge[(k - 128) * 16 + m];
            f[j] = f2bf(v);
        }
        bfrag[c] = f;
    }

    const int nw = (gridDim.x * blockDim.x) >> 6;
    for (int tile = blockIdx.x * (blockDim.x >> 6) + wid; tile < NTILES; tile += nw) {
        const int e   = tile * 16 + m;
        const int src = eidx[e];
        const int dst = eidx[E_EDGES + e];

        // edge_attr row (8 floats)
        const float* er = ea + (size_t)e * 8;
        floatx4 ea0 = ((const floatx4*)er)[0];
        floatx4 ea1 = ((const floatx4*)er)[1];

        // h[src] half this quad needs: i0 = 8*(q&1)
        const float* hr = h + src * 16 + 8 * (q & 1);
        floatx4 h0 = ((const floatx4*)hr)[0];
        floatx4 h1 = ((const floatx4*)hr)[1];
        float hh[8] = {h0.x, h0.y, h0.z, h0.w, h1.x, h1.y, h1.z, h1.w};

        floatx4 acc = {0.f, 0.f, 0.f, 0.f};
        const int hi_t = q >> 1;  // 0 or 1: which t within the pair this quad covers
        #pragma unroll
        for (int c = 0; c < 4; ++c) {
            // t = 2c + (q>>1); select with constant indices (avoid scratch)
            float t_even, t_odd;
            if (c == 0)      { t_even = ea0.x; t_odd = ea0.y; }
            else if (c == 1) { t_even = ea0.z; t_odd = ea0.w; }
            else if (c == 2) { t_even = ea1.x; t_odd = ea1.y; }
            else             { t_even = ea1.z; t_odd = ea1.w; }
            float s = hi_t ? t_odd : t_even;
            short8 af;
            #pragma unroll
            for (int j = 0; j < 8; ++j) af[j] = f2bf(s * hh[j]);
            acc = __builtin_amdgcn_mfma_f32_16x16x32_bf16(af, bfrag[c], acc, 0, 0, 0);
        }
        // chunk 4: k = 128 + 8q + j -> z = h[i=8q+j] for q<2, else 0
        short8 af4;
        #pragma unroll
        for (int j = 0; j < 8; ++j) af4[j] = (q < 2) ? f2bf(hh[j]) : (short)0;
        acc = __builtin_amdgcn_mfma_f32_16x16x32_bf16(af4, bfrag[4], acc, 0, 0, 0);

        // C/D layout: col = lane&15 (=m), row = 4q + r (edge index in tile)
        #pragma unroll
        for (int r = 0; r < 4; ++r) {
            int dr = __shfl(dst, 4 * q + r, 64);
            atomicAdd(out + (size_t)dr * 16 + m, acc[r]);
        }
    }
}

extern "C" void kernel_launch(void* const* d_in, const int* in_sizes, int n_in,
                              void* d_out, int out_size, void* d_ws, size_t ws_size,
                              hipStream_t stream) {
    const float* x        = (const float*)d_in[0];
    const int*   eidx     = (const int*)d_in[1];
    const float* ea       = (const float*)d_in[2];
    const float* ln_gamma = (const float*)d_in[3];
    const float* ln_beta  = (const float*)d_in[4];
    const float* w_edge   = (const float*)d_in[5];
    const float* b_edge   = (const float*)d_in[6];
    const float* root     = (const float*)d_in[7];
    const float* bias     = (const float*)d_in[8];
    float* out = (float*)d_out;
    float* h   = (float*)d_ws;   // N*16 floats = 3.2 MB

    node_kernel<<<(N_NODES + 255) / 256, 256, 0, stream>>>(
        x, ln_gamma, ln_beta, root, bias, h, out);
    edge_kernel<<<1024, 256, 0, stream>>>(eidx, ea, w_edge, b_edge, h, out);
}